// Round 2
// baseline (541.069 us; speedup 1.0000x reference)
//
#include <hip/hip_runtime.h>
#include <stdint.h>

#define T_FULL 2049
#define T_OUT  2048
#define NB     256
#define ND     128
#define U_DIM  32768      // NB*ND
#define NT_BLK 8          // t per gemm block
#define NPART  (T_OUT / NT_BLK)   // 256 partials, one per block

typedef __bf16 bf16x8 __attribute__((ext_vector_type(8)));
typedef float  f32x4  __attribute__((ext_vector_type(4)));

// async global->LDS. LDS dest = uniform base + lane*size.
__device__ __forceinline__ void gl_lds16(const void* g, void* l) {
  void* gnc = const_cast<void*>(g);
  __builtin_amdgcn_global_load_lds(
      (__attribute__((address_space(1))) unsigned int*)gnc,
      (__attribute__((address_space(3))) unsigned int*)l, 16, 0, 0);
}

// ---------------------------------------------------------------------------
// Kernel 1 v7: transpose with 1 KB/row contiguous reads for DRAM page
// efficiency. Block = 64u x 256t: all 16 float4 loads issued up-front
// (per row-quad the full [t0,t0+256) = 1 KB lands together -> near-full
// DRAM page utilization), then 4x the v6 64-t sub-tile pipeline out of
// registers. LDS tile unchanged (64x65 fp32, reads 2-way = free, m136).
// VGPR ~90 -> ~4 blocks/CU (16 waves), MLP/thread 4x.
// ---------------------------------------------------------------------------
#define TP 65
__global__ __launch_bounds__(256) void transpose_split(
    const float* __restrict__ pred, __bf16* __restrict__ H) {
  __shared__ __align__(16) float tile[64 * TP];
  const int u0 = blockIdx.x << 6;   // 64 u per block
  const int t0 = blockIdx.y << 8;   // 256 t per block (t0+255 <= 2047)
  const int tid  = threadIdx.x;
  const int w    = tid >> 6;
  const int l    = tid & 63;

  // thread owns row r; the 4 quad-lanes (c0=0..3) jointly cover the full
  // 1 KB row window: thread reads float4 at floats c0*4 + m*16, m=0..15.
  const int r  = (w << 4) + (l >> 2);
  const int c0 = l & 3;
  const float* src = pred + (size_t)(u0 + r) * T_FULL + t0 + (c0 << 2);
  float4 v[16];
#pragma unroll
  for (int m = 0; m < 16; ++m) v[m] = *(const float4*)(src + (m << 4));

  const int uc = (l & 7) << 3;
#pragma unroll
  for (int j = 0; j < 4; ++j) {       // 4 sub-tiles of 64 t each
    if (j) __syncthreads();           // previous sub-tile's reads done
#pragma unroll
    for (int i = 0; i < 4; ++i)
      *(float4*)&tile[r * TP + (c0 << 2) + (i << 4)] = v[(j << 2) + i];
    __syncthreads();

#pragma unroll
    for (int p = 0; p < 2; ++p) {
      const int tl = (w << 4) + (p << 3) + (l >> 3);
      float x[8];
#pragma unroll
      for (int k = 0; k < 8; ++k) x[k] = tile[(uc + k) * TP + tl];
      bf16x8 hv;
#pragma unroll
      for (int k = 0; k < 8; ++k) hv[k] = (__bf16)x[k];
      *(bf16x8*)(H + (size_t)(t0 + (j << 6) + tl) * U_DIM + u0 + uc) = hv;
    }
  }
}

// tail: the t = 2048 slice (stride-2049 scalar reads, 32768 elements)
__global__ __launch_bounds__(256) void transpose_tail(
    const float* __restrict__ pred, __bf16* __restrict__ H) {
  const int u = (blockIdx.x << 8) + threadIdx.x;
  H[(size_t)T_OUT * U_DIM + u] = (__bf16)pred[(size_t)u * T_FULL + T_OUT];
}

// ---------------------------------------------------------------------------
// Kernel 2 v5 (unchanged): sliding-t persistent blocks. Grid = 256 blocks
// (1/CU), 512 threads (8 waves). Each block owns 8 consecutive t; slices
// double-buffered in 2 x 64 KB LDS with chunk-XOR swizzle. Per t: A-frags ->
// regs from buf[t&1], barrier, prefetch slice t+2 into buf[t&1] (overlaps
// MFMA), MFMA B from buf[(t+1)&1], in-register LSE.
// ---------------------------------------------------------------------------
__global__ __launch_bounds__(512, 2) void gemm_lse_sliding(
    const __bf16* __restrict__ H, float* __restrict__ partials) {
  __shared__ __align__(16) char lds[131072];   // 2 x 64 KB slice buffers

  const int tid  = threadIdx.x;
  const int w    = tid >> 6;     // wave 0..7 -> rows w*32..w*32+31
  const int lane = tid & 63;
  const int q    = lane >> 4;    // 0..3
  const int rr   = lane & 15;    // output col within tile
  const int e    = rr & 7;       // swizzle key
  const int t0   = blockIdx.x << 3;

  // ---- stage one 64 KB slice into buffer bs (0/1): 8 gl_lds16 per lane ----
  auto stage = [&](int slice, int bs) {
    char* dst = lds + (bs << 16);
    const __bf16* src = H + (size_t)slice * U_DIM;
    const int srow4 = lane >> 4;
    const int cst   = lane & 15;
#pragma unroll
    for (int i2 = 0; i2 < 8; ++i2) {
      const int g   = (w << 3) + i2;        // 4-row group 0..63
      const int row = (g << 2) + srow4;
      const int cg  = cst ^ (row & 7);      // global chunk to fetch
      gl_lds16(src + (size_t)row * ND + (cg << 3), dst + (g << 10));
    }
  };

  stage(t0, 0);
  stage(t0 + 1, 1);
  __syncthreads();   // drains both prologue stages

  float lsum = 0.f;
  const int arow0 = (w << 5) + rr;   // A row for rt=0 (rt=1: +16)

  for (int i = 0; i < NT_BLK; ++i) {
    const int pa = i & 1;

    // ---- A fragments -> registers from buf[pa] (slice t0+i) ----
    bf16x8 af[2][4];
    {
      const char* As = lds + (pa << 16);
#pragma unroll
      for (int rt = 0; rt < 2; ++rt) {
        const char* ap = As + (arow0 + (rt << 4)) * 256;
#pragma unroll
        for (int ks = 0; ks < 4; ++ks) {
          const int cix = ((ks << 2) + q) ^ e;
          af[rt][ks] = *(const bf16x8*)(ap + (cix << 4));
        }
      }
    }
    __syncthreads();   // all waves' A reads done; prior prefetch drained

    // ---- prefetch slice t0+i+2 into buf[pa]; overlaps MFMA below ----
    if (i < NT_BLK - 2) stage(t0 + i + 2, pa);

    // ---- MFMA: S[32 rows][256 cols], B = slice t0+i+1 in buf[pa^1] ----
    f32x4 acc[2][16];
#pragma unroll
    for (int rt = 0; rt < 2; ++rt)
#pragma unroll
      for (int ct = 0; ct < 16; ++ct) acc[rt][ct] = f32x4{0.f, 0.f, 0.f, 0.f};

    const __bf16* Bs = (const __bf16*)(lds + ((pa ^ 1) << 16));
#pragma unroll
    for (int ks = 0; ks < 4; ++ks) {
      const int cix = ((ks << 2) + q) ^ e;
      const __bf16* bp = Bs + (size_t)rr * ND + (cix << 3);
#pragma unroll
      for (int ct = 0; ct < 16; ++ct) {
        const bf16x8 bv = *(const bf16x8*)(bp + (ct << 11));  // ct*16 rows
        acc[0][ct] = __builtin_amdgcn_mfma_f32_16x16x32_bf16(af[0][ks], bv, acc[0][ct], 0, 0, 0);
        acc[1][ct] = __builtin_amdgcn_mfma_f32_16x16x32_bf16(af[1][ks], bv, acc[1][ct], 0, 0, 0);
      }
    }

    // ---- in-register LSE. Lane holds rows {w*32+rt*16+q*4+r}, col ct*16+rr.
    float mx[2][4], pp[2][4];
#pragma unroll
    for (int rt = 0; rt < 2; ++rt)
#pragma unroll
      for (int r = 0; r < 4; ++r) mx[rt][r] = -3.0e38f;
#pragma unroll
    for (int rt = 0; rt < 2; ++rt)
#pragma unroll
      for (int ct = 0; ct < 16; ++ct)
#pragma unroll
        for (int r = 0; r < 4; ++r) mx[rt][r] = fmaxf(mx[rt][r], acc[rt][ct][r]);
#pragma unroll
    for (int off = 1; off < 16; off <<= 1)
#pragma unroll
      for (int rt = 0; rt < 2; ++rt)
#pragma unroll
        for (int r = 0; r < 4; ++r)
          mx[rt][r] = fmaxf(mx[rt][r], __shfl_xor(mx[rt][r], off, 64));

#pragma unroll
    for (int rt = 0; rt < 2; ++rt)
#pragma unroll
      for (int r = 0; r < 4; ++r) pp[rt][r] = 0.f;
#pragma unroll
    for (int rt = 0; rt < 2; ++rt)
#pragma unroll
      for (int ct = 0; ct < 16; ++ct)
#pragma unroll
        for (int r = 0; r < 4; ++r)
          pp[rt][r] += __expf(acc[rt][ct][r] - mx[rt][r]);
#pragma unroll
    for (int off = 1; off < 16; off <<= 1)
#pragma unroll
      for (int rt = 0; rt < 2; ++rt)
#pragma unroll
        for (int r = 0; r < 4; ++r) pp[rt][r] += __shfl_xor(pp[rt][r], off, 64);

    // diag row == col: ct = w*2+rt, rr = q*4+r. Each row claimed by exactly
    // one lane (rr>>2 == q, r = rr&3). All indices compile-time (rule #20).
#pragma unroll
    for (int rt = 0; rt < 2; ++rt)
#pragma unroll
      for (int r = 0; r < 4; ++r)
        if (rr == (q << 2) + r) {
          float dv = 0.f;
#pragma unroll
          for (int ct = 0; ct < 16; ++ct)
            if (ct == (w << 1) + rt) dv = acc[rt][ct][r];
          lsum += (mx[rt][r] - dv) + logf(pp[rt][r]);
        }
  }

  // ---- block reduction: wave shfl-sum -> LDS -> thread 0 ----
#pragma unroll
  for (int off = 1; off < 64; off <<= 1) lsum += __shfl_xor(lsum, off, 64);
  __syncthreads();   // all slice-buffer traffic done; reuse LDS as scratch
  float* red = (float*)lds;
  if (lane == 0) red[w] = lsum;
  __syncthreads();
  if (tid == 0) {
    float s = 0.f;
#pragma unroll
    for (int k = 0; k < 8; ++k) s += red[k];
    partials[blockIdx.x] = s;
  }
}

// ---------------------------------------------------------------------------
// Kernel 3: deterministic reduction of NPART partials in fp64, scale 1/(T*B)
// ---------------------------------------------------------------------------
__global__ __launch_bounds__(256) void final_reduce(
    const float* __restrict__ partials, float* __restrict__ out) {
  __shared__ double sh[256];
  double s = 0.0;
  for (int i = threadIdx.x; i < NPART; i += 256) s += (double)partials[i];
  sh[threadIdx.x] = s;
  __syncthreads();
  for (int st = 128; st > 0; st >>= 1) {
    if ((int)threadIdx.x < st) sh[threadIdx.x] += sh[threadIdx.x + st];
    __syncthreads();
  }
  if (threadIdx.x == 0) out[0] = (float)(sh[0] * (1.0 / ((double)T_OUT * NB)));
}

extern "C" void kernel_launch(void* const* d_in, const int* in_sizes, int n_in,
                              void* d_out, int out_size, void* d_ws, size_t ws_size,
                              hipStream_t stream) {
  const float* pred = (const float*)d_in[0];
  float* out = (float*)d_out;
  char* ws = (char*)d_ws;
  __bf16* H = (__bf16*)ws;                                      // 134.3 MB
  float* partials = (float*)(ws + (size_t)T_FULL * U_DIM * 2);  // 1 KB

  dim3 tgrid(U_DIM / 64, T_OUT / 256);  // t in [0,2048), 256 t per block
  transpose_split<<<tgrid, 256, 0, stream>>>(pred, H);
  transpose_tail<<<U_DIM / 256, 256, 0, stream>>>(pred, H);
  gemm_lse_sliding<<<NPART, 512, 0, stream>>>(H, partials);
  final_reduce<<<1, 256, 0, stream>>>(partials, out);
}

// Round 3
// 538.935 us; speedup vs baseline: 1.0040x; 1.0040x over previous
//
#include <hip/hip_runtime.h>
#include <stdint.h>

#define T_FULL 2049
#define T_OUT  2048
#define NB     256
#define ND     128
#define U_DIM  32768      // NB*ND
#define NT_BLK 8          // t per gemm block
#define NPART  (T_OUT / NT_BLK)   // 256 partials, one per block

typedef __bf16 bf16x8 __attribute__((ext_vector_type(8)));
typedef float  f32x4  __attribute__((ext_vector_type(4)));

// async global->LDS. LDS dest = uniform base + lane*size.
__device__ __forceinline__ void gl_lds16(const void* g, void* l) {
  void* gnc = const_cast<void*>(g);
  __builtin_amdgcn_global_load_lds(
      (__attribute__((address_space(1))) unsigned int*)gnc,
      (__attribute__((address_space(3))) unsigned int*)l, 16, 0, 0);
}

// ---------------------------------------------------------------------------
// Kernel 1 v8: v7 with the spill fixed. Block = 64u x 256t, all 16 float4
// loads up-front (1 KB contiguous per row -> DRAM page efficiency), then 4x
// the 64-t sub-tile pipeline out of registers.
// v7 post-mortem: bare __launch_bounds__(256) let the compiler cap VGPRs at
// 32 -> v[16] spilled to scratch -> WRITE_SIZE 134->403 MB, dur 163->221 us.
// __launch_bounds__(256, 4) caps at 4 waves/EU -> 128 VGPRs: 64 data + ~15
// addressing fits, 4 blocks/CU, 256 KB reads in flight per CU.
// ---------------------------------------------------------------------------
#define TP 65
__global__ __launch_bounds__(256, 4) void transpose_split(
    const float* __restrict__ pred, __bf16* __restrict__ H) {
  __shared__ __align__(16) float tile[64 * TP];
  const int u0 = blockIdx.x << 6;   // 64 u per block
  const int t0 = blockIdx.y << 8;   // 256 t per block (t0+255 <= 2047)
  const int tid  = threadIdx.x;
  const int w    = tid >> 6;
  const int l    = tid & 63;

  // thread owns row r; the 4 quad-lanes (c0=0..3) jointly cover the full
  // 1 KB row window: thread reads float4 at floats c0*4 + m*16, m=0..15.
  const int r  = (w << 4) + (l >> 2);
  const int c0 = l & 3;
  const float* src = pred + (size_t)(u0 + r) * T_FULL + t0 + (c0 << 2);
  float4 v[16];
#pragma unroll
  for (int m = 0; m < 16; ++m) v[m] = *(const float4*)(src + (m << 4));

  const int uc = (l & 7) << 3;
#pragma unroll
  for (int j = 0; j < 4; ++j) {       // 4 sub-tiles of 64 t each
    if (j) __syncthreads();           // previous sub-tile's reads done
#pragma unroll
    for (int i = 0; i < 4; ++i)
      *(float4*)&tile[r * TP + (c0 << 2) + (i << 4)] = v[(j << 2) + i];
    __syncthreads();

#pragma unroll
    for (int p = 0; p < 2; ++p) {
      const int tl = (w << 4) + (p << 3) + (l >> 3);
      float x[8];
#pragma unroll
      for (int k = 0; k < 8; ++k) x[k] = tile[(uc + k) * TP + tl];
      bf16x8 hv;
#pragma unroll
      for (int k = 0; k < 8; ++k) hv[k] = (__bf16)x[k];
      *(bf16x8*)(H + (size_t)(t0 + (j << 6) + tl) * U_DIM + u0 + uc) = hv;
    }
  }
}

// tail: the t = 2048 slice (stride-2049 scalar reads, 32768 elements)
__global__ __launch_bounds__(256) void transpose_tail(
    const float* __restrict__ pred, __bf16* __restrict__ H) {
  const int u = (blockIdx.x << 8) + threadIdx.x;
  H[(size_t)T_OUT * U_DIM + u] = (__bf16)pred[(size_t)u * T_FULL + T_OUT];
}

// ---------------------------------------------------------------------------
// Kernel 2 v5 (unchanged): sliding-t persistent blocks. Grid = 256 blocks
// (1/CU), 512 threads (8 waves). Each block owns 8 consecutive t; slices
// double-buffered in 2 x 64 KB LDS with chunk-XOR swizzle. Per t: A-frags ->
// regs from buf[t&1], barrier, prefetch slice t+2 into buf[t&1] (overlaps
// MFMA), MFMA B from buf[(t+1)&1], in-register LSE.
// ---------------------------------------------------------------------------
__global__ __launch_bounds__(512, 2) void gemm_lse_sliding(
    const __bf16* __restrict__ H, float* __restrict__ partials) {
  __shared__ __align__(16) char lds[131072];   // 2 x 64 KB slice buffers

  const int tid  = threadIdx.x;
  const int w    = tid >> 6;     // wave 0..7 -> rows w*32..w*32+31
  const int lane = tid & 63;
  const int q    = lane >> 4;    // 0..3
  const int rr   = lane & 15;    // output col within tile
  const int e    = rr & 7;       // swizzle key
  const int t0   = blockIdx.x << 3;

  // ---- stage one 64 KB slice into buffer bs (0/1): 8 gl_lds16 per lane ----
  auto stage = [&](int slice, int bs) {
    char* dst = lds + (bs << 16);
    const __bf16* src = H + (size_t)slice * U_DIM;
    const int srow4 = lane >> 4;
    const int cst   = lane & 15;
#pragma unroll
    for (int i2 = 0; i2 < 8; ++i2) {
      const int g   = (w << 3) + i2;        // 4-row group 0..63
      const int row = (g << 2) + srow4;
      const int cg  = cst ^ (row & 7);      // global chunk to fetch
      gl_lds16(src + (size_t)row * ND + (cg << 3), dst + (g << 10));
    }
  };

  stage(t0, 0);
  stage(t0 + 1, 1);
  __syncthreads();   // drains both prologue stages

  float lsum = 0.f;
  const int arow0 = (w << 5) + rr;   // A row for rt=0 (rt=1: +16)

  for (int i = 0; i < NT_BLK; ++i) {
    const int pa = i & 1;

    // ---- A fragments -> registers from buf[pa] (slice t0+i) ----
    bf16x8 af[2][4];
    {
      const char* As = lds + (pa << 16);
#pragma unroll
      for (int rt = 0; rt < 2; ++rt) {
        const char* ap = As + (arow0 + (rt << 4)) * 256;
#pragma unroll
        for (int ks = 0; ks < 4; ++ks) {
          const int cix = ((ks << 2) + q) ^ e;
          af[rt][ks] = *(const bf16x8*)(ap + (cix << 4));
        }
      }
    }
    __syncthreads();   // all waves' A reads done; prior prefetch drained

    // ---- prefetch slice t0+i+2 into buf[pa]; overlaps MFMA below ----
    if (i < NT_BLK - 2) stage(t0 + i + 2, pa);

    // ---- MFMA: S[32 rows][256 cols], B = slice t0+i+1 in buf[pa^1] ----
    f32x4 acc[2][16];
#pragma unroll
    for (int rt = 0; rt < 2; ++rt)
#pragma unroll
      for (int ct = 0; ct < 16; ++ct) acc[rt][ct] = f32x4{0.f, 0.f, 0.f, 0.f};

    const __bf16* Bs = (const __bf16*)(lds + ((pa ^ 1) << 16));
#pragma unroll
    for (int ks = 0; ks < 4; ++ks) {
      const int cix = ((ks << 2) + q) ^ e;
      const __bf16* bp = Bs + (size_t)rr * ND + (cix << 3);
#pragma unroll
      for (int ct = 0; ct < 16; ++ct) {
        const bf16x8 bv = *(const bf16x8*)(bp + (ct << 11));  // ct*16 rows
        acc[0][ct] = __builtin_amdgcn_mfma_f32_16x16x32_bf16(af[0][ks], bv, acc[0][ct], 0, 0, 0);
        acc[1][ct] = __builtin_amdgcn_mfma_f32_16x16x32_bf16(af[1][ks], bv, acc[1][ct], 0, 0, 0);
      }
    }

    // ---- in-register LSE. Lane holds rows {w*32+rt*16+q*4+r}, col ct*16+rr.
    float mx[2][4], pp[2][4];
#pragma unroll
    for (int rt = 0; rt < 2; ++rt)
#pragma unroll
      for (int r = 0; r < 4; ++r) mx[rt][r] = -3.0e38f;
#pragma unroll
    for (int rt = 0; rt < 2; ++rt)
#pragma unroll
      for (int ct = 0; ct < 16; ++ct)
#pragma unroll
        for (int r = 0; r < 4; ++r) mx[rt][r] = fmaxf(mx[rt][r], acc[rt][ct][r]);
#pragma unroll
    for (int off = 1; off < 16; off <<= 1)
#pragma unroll
      for (int rt = 0; rt < 2; ++rt)
#pragma unroll
        for (int r = 0; r < 4; ++r)
          mx[rt][r] = fmaxf(mx[rt][r], __shfl_xor(mx[rt][r], off, 64));

#pragma unroll
    for (int rt = 0; rt < 2; ++rt)
#pragma unroll
      for (int r = 0; r < 4; ++r) pp[rt][r] = 0.f;
#pragma unroll
    for (int rt = 0; rt < 2; ++rt)
#pragma unroll
      for (int ct = 0; ct < 16; ++ct)
#pragma unroll
        for (int r = 0; r < 4; ++r)
          pp[rt][r] += __expf(acc[rt][ct][r] - mx[rt][r]);
#pragma unroll
    for (int off = 1; off < 16; off <<= 1)
#pragma unroll
      for (int rt = 0; rt < 2; ++rt)
#pragma unroll
        for (int r = 0; r < 4; ++r) pp[rt][r] += __shfl_xor(pp[rt][r], off, 64);

    // diag row == col: ct = w*2+rt, rr = q*4+r. Each row claimed by exactly
    // one lane (rr>>2 == q, r = rr&3). All indices compile-time (rule #20).
#pragma unroll
    for (int rt = 0; rt < 2; ++rt)
#pragma unroll
      for (int r = 0; r < 4; ++r)
        if (rr == (q << 2) + r) {
          float dv = 0.f;
#pragma unroll
          for (int ct = 0; ct < 16; ++ct)
            if (ct == (w << 1) + rt) dv = acc[rt][ct][r];
          lsum += (mx[rt][r] - dv) + logf(pp[rt][r]);
        }
  }

  // ---- block reduction: wave shfl-sum -> LDS -> thread 0 ----
#pragma unroll
  for (int off = 1; off < 64; off <<= 1) lsum += __shfl_xor(lsum, off, 64);
  __syncthreads();   // all slice-buffer traffic done; reuse LDS as scratch
  float* red = (float*)lds;
  if (lane == 0) red[w] = lsum;
  __syncthreads();
  if (tid == 0) {
    float s = 0.f;
#pragma unroll
    for (int k = 0; k < 8; ++k) s += red[k];
    partials[blockIdx.x] = s;
  }
}

// ---------------------------------------------------------------------------
// Kernel 3: deterministic reduction of NPART partials in fp64, scale 1/(T*B)
// ---------------------------------------------------------------------------
__global__ __launch_bounds__(256) void final_reduce(
    const float* __restrict__ partials, float* __restrict__ out) {
  __shared__ double sh[256];
  double s = 0.0;
  for (int i = threadIdx.x; i < NPART; i += 256) s += (double)partials[i];
  sh[threadIdx.x] = s;
  __syncthreads();
  for (int st = 128; st > 0; st >>= 1) {
    if ((int)threadIdx.x < st) sh[threadIdx.x] += sh[threadIdx.x + st];
    __syncthreads();
  }
  if (threadIdx.x == 0) out[0] = (float)(sh[0] * (1.0 / ((double)T_OUT * NB)));
}

extern "C" void kernel_launch(void* const* d_in, const int* in_sizes, int n_in,
                              void* d_out, int out_size, void* d_ws, size_t ws_size,
                              hipStream_t stream) {
  const float* pred = (const float*)d_in[0];
  float* out = (float*)d_out;
  char* ws = (char*)d_ws;
  __bf16* H = (__bf16*)ws;                                      // 134.3 MB
  float* partials = (float*)(ws + (size_t)T_FULL * U_DIM * 2);  // 1 KB

  dim3 tgrid(U_DIM / 64, T_OUT / 256);  // t in [0,2048), 256 t per block
  transpose_split<<<tgrid, 256, 0, stream>>>(pred, H);
  transpose_tail<<<U_DIM / 256, 256, 0, stream>>>(pred, H);
  gemm_lse_sliding<<<NPART, 512, 0, stream>>>(H, partials);
  final_reduce<<<1, 256, 0, stream>>>(partials, out);
}

// Round 5
// 497.836 us; speedup vs baseline: 1.0868x; 1.0826x over previous
//
#include <hip/hip_runtime.h>
#include <stdint.h>

#define T_FULL 2049
#define T_OUT  2048
#define NB     256
#define ND     128
#define U_DIM  32768      // NB*ND
#define NT_BLK 8          // t per gemm block
#define NGBLK  ((T_OUT / NT_BLK) * 2)   // 512 blocks: 256 t-groups x 2 c-halves
#define NPART  NGBLK                    // merge partials, one per merge block

typedef __bf16 bf16x8 __attribute__((ext_vector_type(8)));
typedef float  f32x4  __attribute__((ext_vector_type(4)));

// async global->LDS. LDS dest = uniform base + lane*size.
__device__ __forceinline__ void gl_lds16(const void* g, void* l) {
  void* gnc = const_cast<void*>(g);
  __builtin_amdgcn_global_load_lds(
      (__attribute__((address_space(1))) unsigned int*)gnc,
      (__attribute__((address_space(3))) unsigned int*)l, 16, 0, 0);
}

// ---------------------------------------------------------------------------
// Kernel 1 v6 (reverted; v7/v8's 16-float4 staging spilled to scratch both
// times: WRITE_SIZE 134->403 MB, VGPR stuck at 32/36). Block = 64u x 64t,
// LDS 64x65 fp32 (16.6 KB) -> ~8 blocks/CU. 64-B read segments, 128-B write
// segments, LDS reads exactly 2-way (free, m136). Known 163 us.
// ---------------------------------------------------------------------------
#define TP 65
__global__ __launch_bounds__(256) void transpose_split(
    const float* __restrict__ pred, __bf16* __restrict__ H) {
  __shared__ __align__(16) float tile[64 * TP];
  const int u0 = blockIdx.x << 6;   // 64 u per block
  const int t0 = blockIdx.y << 6;   // 64 t per block (t0+63 <= 2047)
  const int tid  = threadIdx.x;
  const int w    = tid >> 6;
  const int l    = tid & 63;

  const int r  = (w << 4) + (l >> 2);
  const int c0 = l & 3;
  const float* src = pred + (size_t)(u0 + r) * T_FULL + t0 + (c0 << 2);
  float4 v[4];
#pragma unroll
  for (int i = 0; i < 4; ++i) v[i] = *(const float4*)(src + (i << 4));
#pragma unroll
  for (int i = 0; i < 4; ++i)
    *(float4*)&tile[r * TP + (c0 << 2) + (i << 4)] = v[i];
  __syncthreads();

  const int uc = (l & 7) << 3;
#pragma unroll
  for (int p = 0; p < 2; ++p) {
    const int tl = (w << 4) + (p << 3) + (l >> 3);
    float x[8];
#pragma unroll
    for (int k = 0; k < 8; ++k) x[k] = tile[(uc + k) * TP + tl];
    bf16x8 hv;
#pragma unroll
    for (int k = 0; k < 8; ++k) hv[k] = (__bf16)x[k];
    *(bf16x8*)(H + (size_t)(t0 + tl) * U_DIM + u0 + uc) = hv;
  }
}

// tail: the t = 2048 slice (stride-2049 scalar reads, 32768 elements)
__global__ __launch_bounds__(256) void transpose_tail(
    const float* __restrict__ pred, __bf16* __restrict__ H) {
  const int u = (blockIdx.x << 8) + threadIdx.x;
  H[(size_t)T_OUT * U_DIM + u] = (__bf16)pred[(size_t)u * T_FULL + T_OUT];
}

// ---------------------------------------------------------------------------
// Kernel 2 v6: c-split sliding gemm. Block = (t-group, c-half): 512 blocks,
// 512 threads (8 waves), LDS = 2 x 32 KB B-half double-buffer -> 2 blocks/CU,
// 4 waves/SIMD (v5 was 128 KB -> 1 block/CU, 2 waves/SIMD, latency-exposed).
// A-fragments read directly from global (H is L3-resident) -> one barrier per
// iteration. Per iter i: barrier (B ready), prefetch B-half t0+i+2, A loads,
// MFMA (setprio-wrapped), in-register row max/sum over this c-half, write
// per-row (m,s) [+ fz from the diag-owning half]. merge_lse combines halves.
// ---------------------------------------------------------------------------
__global__ __launch_bounds__(512, 4) void gemm_lse_chalf(
    const __bf16* __restrict__ H, float* __restrict__ Mbuf,
    float* __restrict__ Sbuf, float* __restrict__ FZ) {
  __shared__ __align__(16) char lds[65536];   // 2 x 32 KB B-half buffers

  const int tid  = threadIdx.x;
  const int w    = tid >> 6;     // wave 0..7 -> rows w*32..w*32+31
  const int lane = tid & 63;
  const int q    = lane >> 4;    // 0..3
  const int rr   = lane & 15;    // output col within 16-tile
  const int e    = rr & 7;       // swizzle key
  const int blk  = blockIdx.x;
  const int t0   = (blk >> 1) << 3;   // t-group
  const int h    = blk & 1;           // c-half: cols [128h, 128h+128)

  // ---- stage one 32 KB B-half (rows 128h..128h+127 of slice) into buf bs ----
  auto stage = [&](int slice, int bs) {
    char* dst = lds + (bs << 15);
    const __bf16* src = H + (size_t)slice * U_DIM + ((size_t)(h << 7)) * ND;
    const int srow4 = lane >> 4;
    const int cst   = lane & 15;
#pragma unroll
    for (int i2 = 0; i2 < 4; ++i2) {
      const int g   = (w << 2) + i2;        // 4-row group 0..31
      const int row = (g << 2) + srow4;     // local row 0..127
      const int cg  = cst ^ (row & 7);      // global chunk to fetch (swizzle)
      gl_lds16(src + (size_t)row * ND + (cg << 3), dst + (g << 10));
    }
  };

  stage(t0 + 1, 1);   // B for iter 0 lives in buf[1]

  const int arow0 = (w << 5) + rr;   // A row for rt=0 (rt=1: +16)

  for (int i = 0; i < NT_BLK; ++i) {
    const int t_idx = t0 + i;
    __syncthreads();  // buf[(i+1)&1] staged & visible; buf[i&1]'s readers done

    // ---- prefetch B-half for iter i+1 (slice t0+i+2) into buf[i&1] ----
    if (i < NT_BLK - 1) stage(t_idx + 2, i & 1);

    // ---- A fragments direct from global (L3-resident) ----
    bf16x8 af[2][4];
    {
      const __bf16* Ha = H + (size_t)t_idx * U_DIM;
#pragma unroll
      for (int rt = 0; rt < 2; ++rt) {
        const __bf16* ap = Ha + (size_t)(arow0 + (rt << 4)) * ND;
#pragma unroll
        for (int ks = 0; ks < 4; ++ks)
          af[rt][ks] = *(const bf16x8*)(ap + (ks << 5) + (q << 3));
      }
    }

    // ---- MFMA: S[32 rows][128 cols-of-half], B from buf[(i+1)&1] ----
    f32x4 acc[2][8];
#pragma unroll
    for (int rt = 0; rt < 2; ++rt)
#pragma unroll
      for (int ct = 0; ct < 8; ++ct) acc[rt][ct] = f32x4{0.f, 0.f, 0.f, 0.f};

    const __bf16* Bs = (const __bf16*)(lds + (((i + 1) & 1) << 15));
    __builtin_amdgcn_s_setprio(1);
#pragma unroll
    for (int ks = 0; ks < 4; ++ks) {
      const int cix = ((ks << 2) + q) ^ e;
      const __bf16* bp = Bs + (size_t)rr * ND + (cix << 3);
#pragma unroll
      for (int ct = 0; ct < 8; ++ct) {
        const bf16x8 bv = *(const bf16x8*)(bp + (ct << 11));  // +ct*16 rows
        acc[0][ct] = __builtin_amdgcn_mfma_f32_16x16x32_bf16(af[0][ks], bv, acc[0][ct], 0, 0, 0);
        acc[1][ct] = __builtin_amdgcn_mfma_f32_16x16x32_bf16(af[1][ks], bv, acc[1][ct], 0, 0, 0);
      }
    }
    __builtin_amdgcn_s_setprio(0);

    // ---- per-half LSE. Lane holds rows {w*32+rt*16+q*4+r}, col ct*16+rr. ---
    float mx[2][4], pp[2][4];
#pragma unroll
    for (int rt = 0; rt < 2; ++rt)
#pragma unroll
      for (int r = 0; r < 4; ++r) mx[rt][r] = -3.0e38f;
#pragma unroll
    for (int rt = 0; rt < 2; ++rt)
#pragma unroll
      for (int ct = 0; ct < 8; ++ct)
#pragma unroll
        for (int r = 0; r < 4; ++r) mx[rt][r] = fmaxf(mx[rt][r], acc[rt][ct][r]);
#pragma unroll
    for (int off = 1; off < 16; off <<= 1)
#pragma unroll
      for (int rt = 0; rt < 2; ++rt)
#pragma unroll
        for (int r = 0; r < 4; ++r)
          mx[rt][r] = fmaxf(mx[rt][r], __shfl_xor(mx[rt][r], off, 64));

#pragma unroll
    for (int rt = 0; rt < 2; ++rt)
#pragma unroll
      for (int r = 0; r < 4; ++r) pp[rt][r] = 0.f;
#pragma unroll
    for (int rt = 0; rt < 2; ++rt)
#pragma unroll
      for (int ct = 0; ct < 8; ++ct)
#pragma unroll
        for (int r = 0; r < 4; ++r)
          pp[rt][r] += __expf(acc[rt][ct][r] - mx[rt][r]);
#pragma unroll
    for (int off = 1; off < 16; off <<= 1)
#pragma unroll
      for (int rt = 0; rt < 2; ++rt)
#pragma unroll
        for (int r = 0; r < 4; ++r) pp[rt][r] += __shfl_xor(pp[rt][r], off, 64);

    // ---- write per-row (m, s): lanes rr==0, one per q-group ----
    if (rr == 0) {
      const int msbase = (((h << 11) + t_idx) << 8);  // (h*2048 + t)*256
#pragma unroll
      for (int rt = 0; rt < 2; ++rt)
#pragma unroll
        for (int r = 0; r < 4; ++r) {
          const int row = (w << 5) + (rt << 4) + (q << 2) + r;
          Mbuf[msbase + row] = mx[rt][r];
          Sbuf[msbase + row] = pp[rt][r];
        }
    }

    // ---- diag fz: col (=128h+ct*16+rr) == row. Only the owning half. ----
#pragma unroll
    for (int rt = 0; rt < 2; ++rt) {
      const int ctd = ((w << 1) + rt) - (h << 3);   // 2w+rt-8h
      if (ctd >= 0 && ctd < 8) {
#pragma unroll
        for (int r = 0; r < 4; ++r)
          if (rr == (q << 2) + r) {
            float dv = 0.f;
#pragma unroll
            for (int ct = 0; ct < 8; ++ct)
              if (ct == ctd) dv = acc[rt][ct][r];
            FZ[(t_idx << 8) + (w << 5) + (rt << 4) + (q << 2) + r] = dv;
          }
      }
    }
  }
}

// ---------------------------------------------------------------------------
// Kernel 3: merge the two c-halves per (t,row): stable LSE combine, minus fz.
// 512 blocks x 256 threads, 4 rows/thread; block partial -> partials[blk].
// ---------------------------------------------------------------------------
__global__ __launch_bounds__(256) void merge_lse(
    const float* __restrict__ Mbuf, const float* __restrict__ Sbuf,
    const float* __restrict__ FZ, float* __restrict__ partials) {
  float s = 0.f;
  const int base = (blockIdx.x << 10) + threadIdx.x;
#pragma unroll
  for (int k = 0; k < 4; ++k) {
    const int idx = base + (k << 8);               // t*256 + row, 0..2^19
    const float m0 = Mbuf[idx];
    const float m1 = Mbuf[idx + (1 << 19)];
    const float s0 = Sbuf[idx];
    const float s1 = Sbuf[idx + (1 << 19)];
    const float fz = FZ[idx];
    const float M  = fmaxf(m0, m1);
    s += (M - fz) + logf(__expf(m0 - M) * s0 + __expf(m1 - M) * s1);
  }
  __shared__ float sh[256];
  sh[threadIdx.x] = s;
  __syncthreads();
  for (int st = 128; st > 0; st >>= 1) {
    if ((int)threadIdx.x < st) sh[threadIdx.x] += sh[threadIdx.x + st];
    __syncthreads();
  }
  if (threadIdx.x == 0) partials[blockIdx.x] = sh[0];
}

// ---------------------------------------------------------------------------
// Kernel 4: deterministic reduction of NPART partials in fp64, scale 1/(T*B)
// ---------------------------------------------------------------------------
__global__ __launch_bounds__(256) void final_reduce(
    const float* __restrict__ partials, float* __restrict__ out) {
  __shared__ double sh[256];
  double s = 0.0;
  for (int i = threadIdx.x; i < NPART; i += 256) s += (double)partials[i];
  sh[threadIdx.x] = s;
  __syncthreads();
  for (int st = 128; st > 0; st >>= 1) {
    if ((int)threadIdx.x < st) sh[threadIdx.x] += sh[threadIdx.x + st];
    __syncthreads();
  }
  if (threadIdx.x == 0) out[0] = (float)(sh[0] * (1.0 / ((double)T_OUT * NB)));
}

extern "C" void kernel_launch(void* const* d_in, const int* in_sizes, int n_in,
                              void* d_out, int out_size, void* d_ws, size_t ws_size,
                              hipStream_t stream) {
  const float* pred = (const float*)d_in[0];
  float* out = (float*)d_out;
  char* ws = (char*)d_ws;
  __bf16* H = (__bf16*)ws;                                   // 134.3 MB
  float* Mbuf = (float*)(ws + (size_t)T_FULL * U_DIM * 2);   // 4 MB (2 planes)
  float* Sbuf = Mbuf + (1 << 20);                            // 4 MB
  float* FZ   = Sbuf + (1 << 20);                            // 2 MB
  float* partials = FZ + (1 << 19);                          // 2 KB

  dim3 tgrid(U_DIM / 64, T_OUT / 64);  // t in [0,2048)
  transpose_split<<<tgrid, 256, 0, stream>>>(pred, H);
  transpose_tail<<<U_DIM / 256, 256, 0, stream>>>(pred, H);
  gemm_lse_chalf<<<NGBLK, 512, 0, stream>>>(H, Mbuf, Sbuf, FZ);
  merge_lse<<<NGBLK, 256, 0, stream>>>(Mbuf, Sbuf, FZ, partials);
  final_reduce<<<1, 256, 0, stream>>>(partials, out);
}

// Round 6
// 463.135 us; speedup vs baseline: 1.1683x; 1.0749x over previous
//
#include <hip/hip_runtime.h>
#include <stdint.h>

#define T_FULL 2049
#define T_OUT  2048
#define NB     256
#define ND     128
#define U_DIM  32768      // NB*ND
#define NT_BLK 8          // t per gemm block
#define NPART  (T_OUT / NT_BLK)   // 256 partials, one per block

typedef __bf16 bf16x8 __attribute__((ext_vector_type(8)));
typedef float  f32x4  __attribute__((ext_vector_type(4)));

// async global->LDS. LDS dest = uniform base + lane*size.
__device__ __forceinline__ void gl_lds16(const void* g, void* l) {
  void* gnc = const_cast<void*>(g);
  __builtin_amdgcn_global_load_lds(
      (__attribute__((address_space(1))) unsigned int*)gnc,
      (__attribute__((address_space(3))) unsigned int*)l, 16, 0, 0);
}

// ---------------------------------------------------------------------------
// Kernel 1 v9: read-page-efficiency transpose. Block = 64u x 256t, 512 thr.
// Phase 1: each (row r, lane-octet c0) reads 8 NAMED float4s covering the
// full 1 KB row window [t0, t0+256) -> near-full DRAM page use on the read
// side (v6 read only 256 B per 8196-B-strided row visit). No register
// arrays (v7/v8 spilled: WRITE_SIZE 134->403 MB). Phase 2: v6-proven
// subtile pattern x4. Tile fp32 [64][257] = 65.8 KB (odd pitch -> bank =
// (u+t)%32, 2-way free) -> 2 blocks/CU.
// ---------------------------------------------------------------------------
#define TPW 257
__global__ __launch_bounds__(512, 4) void transpose_split(
    const float* __restrict__ pred, __bf16* __restrict__ H) {
  __shared__ __align__(16) float tile[64 * TPW];   // 65792 B
  const int u0 = blockIdx.x << 6;   // 64 u per block
  const int t0 = blockIdx.y << 8;   // 256 t per block (t0+255 <= 2047)
  const int tid = threadIdx.x;

  // ---- phase 1: thread (r, c0) loads float4 at t = c0*4 + i*32, i=0..7 ----
  const int r  = tid >> 3;          // 0..63
  const int c0 = tid & 7;
  const float* src = pred + (size_t)(u0 + r) * T_FULL + t0 + (c0 << 2);
  const float4 a0 = *(const float4*)(src +   0);
  const float4 a1 = *(const float4*)(src +  32);
  const float4 a2 = *(const float4*)(src +  64);
  const float4 a3 = *(const float4*)(src +  96);
  const float4 a4 = *(const float4*)(src + 128);
  const float4 a5 = *(const float4*)(src + 160);
  const float4 a6 = *(const float4*)(src + 192);
  const float4 a7 = *(const float4*)(src + 224);
  float* trow = &tile[r * TPW + (c0 << 2)];
  *(float4*)(trow +   0) = a0;
  *(float4*)(trow +  32) = a1;
  *(float4*)(trow +  64) = a2;
  *(float4*)(trow +  96) = a3;
  *(float4*)(trow + 128) = a4;
  *(float4*)(trow + 160) = a5;
  *(float4*)(trow + 192) = a6;
  *(float4*)(trow + 224) = a7;
  __syncthreads();

  // ---- phase 2: 4 subtiles of 64 t, v6 pattern; 2 waves per subtile ----
  const int w  = tid >> 6;          // wave 0..7
  const int l  = tid & 63;
  const int s  = w >> 1;            // subtile 0..3
  const int uc = (l & 7) << 3;      // u-chunk base 0..56
#pragma unroll
  for (int p2 = 0; p2 < 4; ++p2) {
    const int tl = ((w & 1) << 5) + (p2 << 3) + (l >> 3);   // 0..63
    float x[8];
#pragma unroll
    for (int k = 0; k < 8; ++k) x[k] = tile[(uc + k) * TPW + (s << 6) + tl];
    bf16x8 hv;
#pragma unroll
    for (int k = 0; k < 8; ++k) hv[k] = (__bf16)x[k];
    *(bf16x8*)(H + (size_t)(t0 + (s << 6) + tl) * U_DIM + u0 + uc) = hv;
  }
}

// tail: the t = 2048 slice (stride-2049 scalar reads, 32768 elements)
__global__ __launch_bounds__(256) void transpose_tail(
    const float* __restrict__ pred, __bf16* __restrict__ H) {
  const int u = (blockIdx.x << 8) + threadIdx.x;
  H[(size_t)T_OUT * U_DIM + u] = (__bf16)pred[(size_t)u * T_FULL + T_OUT];
}

// ---------------------------------------------------------------------------
// Kernel 2 v5 (reverted from v6 c-split: round-5 showed v6+merge was a net
// -20 us regression vs v5). Sliding-t persistent blocks. Grid = 256 blocks
// (1/CU), 512 threads (8 waves). Each block owns 8 consecutive t; slices
// double-buffered in 2 x 64 KB LDS with chunk-XOR swizzle. Per t: A-frags ->
// regs from buf[t&1], barrier, prefetch slice t+2 into buf[t&1] (overlaps
// MFMA), MFMA B from buf[(t+1)&1], in-register LSE.
// ---------------------------------------------------------------------------
__global__ __launch_bounds__(512, 2) void gemm_lse_sliding(
    const __bf16* __restrict__ H, float* __restrict__ partials) {
  __shared__ __align__(16) char lds[131072];   // 2 x 64 KB slice buffers

  const int tid  = threadIdx.x;
  const int w    = tid >> 6;     // wave 0..7 -> rows w*32..w*32+31
  const int lane = tid & 63;
  const int q    = lane >> 4;    // 0..3
  const int rr   = lane & 15;    // output col within tile
  const int e    = rr & 7;       // swizzle key
  const int t0   = blockIdx.x << 3;

  // ---- stage one 64 KB slice into buffer bs (0/1): 8 gl_lds16 per lane ----
  auto stage = [&](int slice, int bs) {
    char* dst = lds + (bs << 16);
    const __bf16* src = H + (size_t)slice * U_DIM;
    const int srow4 = lane >> 4;
    const int cst   = lane & 15;
#pragma unroll
    for (int i2 = 0; i2 < 8; ++i2) {
      const int g   = (w << 3) + i2;        // 4-row group 0..63
      const int row = (g << 2) + srow4;
      const int cg  = cst ^ (row & 7);      // global chunk to fetch
      gl_lds16(src + (size_t)row * ND + (cg << 3), dst + (g << 10));
    }
  };

  stage(t0, 0);
  stage(t0 + 1, 1);
  __syncthreads();   // drains both prologue stages

  float lsum = 0.f;
  const int arow0 = (w << 5) + rr;   // A row for rt=0 (rt=1: +16)

  for (int i = 0; i < NT_BLK; ++i) {
    const int pa = i & 1;

    // ---- A fragments -> registers from buf[pa] (slice t0+i) ----
    bf16x8 af[2][4];
    {
      const char* As = lds + (pa << 16);
#pragma unroll
      for (int rt = 0; rt < 2; ++rt) {
        const char* ap = As + (arow0 + (rt << 4)) * 256;
#pragma unroll
        for (int ks = 0; ks < 4; ++ks) {
          const int cix = ((ks << 2) + q) ^ e;
          af[rt][ks] = *(const bf16x8*)(ap + (cix << 4));
        }
      }
    }
    __syncthreads();   // all waves' A reads done; prior prefetch drained

    // ---- prefetch slice t0+i+2 into buf[pa]; overlaps MFMA below ----
    if (i < NT_BLK - 2) stage(t0 + i + 2, pa);

    // ---- MFMA: S[32 rows][256 cols], B = slice t0+i+1 in buf[pa^1] ----
    f32x4 acc[2][16];
#pragma unroll
    for (int rt = 0; rt < 2; ++rt)
#pragma unroll
      for (int ct = 0; ct < 16; ++ct) acc[rt][ct] = f32x4{0.f, 0.f, 0.f, 0.f};

    const __bf16* Bs = (const __bf16*)(lds + ((pa ^ 1) << 16));
#pragma unroll
    for (int ks = 0; ks < 4; ++ks) {
      const int cix = ((ks << 2) + q) ^ e;
      const __bf16* bp = Bs + (size_t)rr * ND + (cix << 3);
#pragma unroll
      for (int ct = 0; ct < 16; ++ct) {
        const bf16x8 bv = *(const bf16x8*)(bp + (ct << 11));  // ct*16 rows
        acc[0][ct] = __builtin_amdgcn_mfma_f32_16x16x32_bf16(af[0][ks], bv, acc[0][ct], 0, 0, 0);
        acc[1][ct] = __builtin_amdgcn_mfma_f32_16x16x32_bf16(af[1][ks], bv, acc[1][ct], 0, 0, 0);
      }
    }

    // ---- in-register LSE. Lane holds rows {w*32+rt*16+q*4+r}, col ct*16+rr.
    float mx[2][4], pp[2][4];
#pragma unroll
    for (int rt = 0; rt < 2; ++rt)
#pragma unroll
      for (int r = 0; r < 4; ++r) mx[rt][r] = -3.0e38f;
#pragma unroll
    for (int rt = 0; rt < 2; ++rt)
#pragma unroll
      for (int ct = 0; ct < 16; ++ct)
#pragma unroll
        for (int r = 0; r < 4; ++r) mx[rt][r] = fmaxf(mx[rt][r], acc[rt][ct][r]);
#pragma unroll
    for (int off = 1; off < 16; off <<= 1)
#pragma unroll
      for (int rt = 0; rt < 2; ++rt)
#pragma unroll
        for (int r = 0; r < 4; ++r)
          mx[rt][r] = fmaxf(mx[rt][r], __shfl_xor(mx[rt][r], off, 64));

#pragma unroll
    for (int rt = 0; rt < 2; ++rt)
#pragma unroll
      for (int r = 0; r < 4; ++r) pp[rt][r] = 0.f;
#pragma unroll
    for (int rt = 0; rt < 2; ++rt)
#pragma unroll
      for (int ct = 0; ct < 16; ++ct)
#pragma unroll
        for (int r = 0; r < 4; ++r)
          pp[rt][r] += __expf(acc[rt][ct][r] - mx[rt][r]);
#pragma unroll
    for (int off = 1; off < 16; off <<= 1)
#pragma unroll
      for (int rt = 0; rt < 2; ++rt)
#pragma unroll
        for (int r = 0; r < 4; ++r) pp[rt][r] += __shfl_xor(pp[rt][r], off, 64);

    // diag row == col: ct = w*2+rt, rr = q*4+r. Each row claimed by exactly
    // one lane (rr>>2 == q, r = rr&3). All indices compile-time (rule #20).
#pragma unroll
    for (int rt = 0; rt < 2; ++rt)
#pragma unroll
      for (int r = 0; r < 4; ++r)
        if (rr == (q << 2) + r) {
          float dv = 0.f;
#pragma unroll
          for (int ct = 0; ct < 16; ++ct)
            if (ct == (w << 1) + rt) dv = acc[rt][ct][r];
          lsum += (mx[rt][r] - dv) + logf(pp[rt][r]);
        }
  }

  // ---- block reduction: wave shfl-sum -> LDS -> thread 0 ----
#pragma unroll
  for (int off = 1; off < 64; off <<= 1) lsum += __shfl_xor(lsum, off, 64);
  __syncthreads();   // all slice-buffer traffic done; reuse LDS as scratch
  float* red = (float*)lds;
  if (lane == 0) red[w] = lsum;
  __syncthreads();
  if (tid == 0) {
    float s = 0.f;
#pragma unroll
    for (int k = 0; k < 8; ++k) s += red[k];
    partials[blockIdx.x] = s;
  }
}

// ---------------------------------------------------------------------------
// Kernel 3: deterministic reduction of NPART partials in fp64, scale 1/(T*B)
// ---------------------------------------------------------------------------
__global__ __launch_bounds__(256) void final_reduce(
    const float* __restrict__ partials, float* __restrict__ out) {
  __shared__ double sh[256];
  double s = 0.0;
  for (int i = threadIdx.x; i < NPART; i += 256) s += (double)partials[i];
  sh[threadIdx.x] = s;
  __syncthreads();
  for (int st = 128; st > 0; st >>= 1) {
    if ((int)threadIdx.x < st) sh[threadIdx.x] += sh[threadIdx.x + st];
    __syncthreads();
  }
  if (threadIdx.x == 0) out[0] = (float)(sh[0] * (1.0 / ((double)T_OUT * NB)));
}

extern "C" void kernel_launch(void* const* d_in, const int* in_sizes, int n_in,
                              void* d_out, int out_size, void* d_ws, size_t ws_size,
                              hipStream_t stream) {
  const float* pred = (const float*)d_in[0];
  float* out = (float*)d_out;
  char* ws = (char*)d_ws;
  __bf16* H = (__bf16*)ws;                                      // 134.3 MB
  float* partials = (float*)(ws + (size_t)T_FULL * U_DIM * 2);  // 1 KB

  dim3 tgrid(U_DIM / 64, T_OUT / 256);  // 64u x 256t per block
  transpose_split<<<tgrid, 512, 0, stream>>>(pred, H);
  transpose_tail<<<U_DIM / 256, 256, 0, stream>>>(pred, H);
  gemm_lse_sliding<<<NPART, 512, 0, stream>>>(H, partials);
  final_reduce<<<1, 256, 0, stream>>>(partials, out);
}